// Round 20
// baseline (26.275 us; speedup 1.0000x reference)
//
#include <hip/hip_runtime.h>
#include <stdint.h>

// B=4, T=1024, D=64 causal attention probs + deterministic JAX dropout.
// R20: single kernel; ALL K MFMA-fragments staged in LDS (128 KB) so the
// hot loop has ZERO global loads (ds_read_b128 ~12cyc vs L2 ~200cyc — the
// surviving suspect for the occupancy-insensitive 12us stall, R14/R19 null).
// 256 blocks x 1024 thr; block = 16 interleaved rows {g+64m}; wave owns 4 jt
// tiles; no-max softmax (S in [0,8]); int-compare threefry keep test.
#define TT 1024
#define BB 4

typedef __fp16 fp16x2 __attribute__((ext_vector_type(2)));
typedef __fp16 fp16x8 __attribute__((ext_vector_type(8)));
typedef float  floatx4 __attribute__((ext_vector_type(4)));
union U32H2 { uint32_t u; fp16x2 h; };
union U4H8  { uint4 u; fp16x8 h; };

__device__ __forceinline__ uint32_t rotl32(uint32_t x, int d) {
  return (x << d) | (x >> (32 - d));
}

// JAX partitionable threefry (key(42)): bits = o0^o1 of tf2x32((0,42),(0,i)).
// keep = u<0.8f <=> bits < 6710887<<9.  [verified R1/R19]
__device__ __forceinline__ bool keep_at(uint32_t i) {
  uint32_t x0 = 0u, x1 = i;
  const uint32_t ks0 = 0u, ks1 = 42u;
  const uint32_t ks2 = 0x1BD11BDAu ^ ks0 ^ ks1;
  x0 += ks0; x1 += ks1;
#define R4(a,b,c,d)                              \
  x0 += x1; x1 = rotl32(x1,(a)); x1 ^= x0;       \
  x0 += x1; x1 = rotl32(x1,(b)); x1 ^= x0;       \
  x0 += x1; x1 = rotl32(x1,(c)); x1 ^= x0;       \
  x0 += x1; x1 = rotl32(x1,(d)); x1 ^= x0;
  R4(13,15,26,6)   x0 += ks1; x1 += ks2 + 1u;
  R4(17,29,16,24)  x0 += ks2; x1 += ks0 + 2u;
  R4(13,15,26,6)   x0 += ks0; x1 += ks1 + 3u;
  R4(17,29,16,24)  x0 += ks1; x1 += ks2 + 4u;
  R4(13,15,26,6)   x0 += ks2; x1 += ks0 + 5u;
#undef R4
  return (x0 ^ x1) < 3435974144u;   // 6710887 << 9
}

__device__ __forceinline__ uint32_t pack2(float x, float y) {
  U32H2 t; t.h = __builtin_amdgcn_cvt_pkrtz(x, y);
  return t.u;
}
__device__ __forceinline__ U4H8 pack8(float4 f0, float4 f1) {
  U4H8 d;
  d.u.x = pack2(f0.x, f0.y); d.u.y = pack2(f0.z, f0.w);
  d.u.z = pack2(f1.x, f1.y); d.u.w = pack2(f1.z, f1.w);
  return d;
}

template <int CTRL>
__device__ __forceinline__ float adddpp(float x) {
  const int s =
      __builtin_amdgcn_update_dpp(0, __float_as_int(x), CTRL, 0xF, 0xF, true);
  return x + __int_as_float(s);
}
// sum over the 16 lanes of a (l>>4) group  [verified R11-R19]
__device__ __forceinline__ float radd16(float a) {
  a = adddpp<0xB1>(a);  a = adddpp<0x4E>(a);
  a = adddpp<0x141>(a); a = adddpp<0x140>(a);
  return a;
}

__global__ __launch_bounds__(1024)
void attn_kernel(const float* __restrict__ Q, const float* __restrict__ K,
                 float* __restrict__ O) {
  __shared__ uint4 KS[8192];          // all K frags for batch b: 128 KB
  __shared__ float redS[16][16];

  const int tid  = threadIdx.x;
  const int wv   = tid >> 6, ln = tid & 63;   // wv 0..15
  const int colL = ln & 15;
  const int kgrp = ln >> 4;
  const int g    = blockIdx.x & 63;
  const int b    = blockIdx.x >> 6;

  const float4* Qf = reinterpret_cast<const float4*>(Q) + (size_t)b * TT * 16;
  const float4* Kf = reinterpret_cast<const float4*>(K) + (size_t)b * TT * 16;

  // ---- stage all K fragments: 8 frags/thread, fp32 -> f16 -> LDS ----
  // frag f = (tile*2 + c)*64 + l; lane l supplies B[k=c*32+(l>>4)*8+i][col=tile*16+(l&15)]
#pragma unroll
  for (int w = 0; w < 8; ++w) {
    const int f    = w * 1024 + tid;
    const int tile = f >> 7, cc = (f >> 6) & 1, l = f & 63;
    const int row  = tile * 16 + (l & 15);
    const float4* s = Kf + row * 16 + cc * 8 + (l >> 4) * 2;
    KS[f] = pack8(s[0], s[1]).u;
  }

  // ---- A-frags (q rows g+64m) direct from fp32  [verified R13] ----
  const int arow = g + 64 * (ln & 15);
  const U4H8 qa0 = pack8(Qf[arow * 16 + kgrp * 2],     Qf[arow * 16 + kgrp * 2 + 1]);
  const U4H8 qa1 = pack8(Qf[arow * 16 + 8 + kgrp * 2], Qf[arow * 16 + 8 + kgrp * 2 + 1]);

  int rowD[4]; uint32_t obase[4];
#pragma unroll
  for (int r = 0; r < 4; ++r) {
    rowD[r]  = g + 64 * (kgrp * 4 + r);
    obase[r] = ((uint32_t)b << 20) | ((uint32_t)rowD[r] << 10);
  }

  __syncthreads();                    // K frags visible

  // ---- pass A: 4 jt tiles per wave, B-frags from LDS ----
  float p[4][4];
  float sAcc[4] = {0.f, 0.f, 0.f, 0.f};
#pragma unroll
  for (int it = 0; it < 4; ++it) {
    const int jt = it * 16 + wv;
    U4H8 kb0, kb1;
    kb0.u = KS[(jt * 2 + 0) * 64 + ln];
    kb1.u = KS[(jt * 2 + 1) * 64 + ln];
    floatx4 acc = {0.f, 0.f, 0.f, 0.f};
    acc = __builtin_amdgcn_mfma_f32_16x16x32_f16(qa0.h, kb0.h, acc, 0, 0, 0);
    acc = __builtin_amdgcn_mfma_f32_16x16x32_f16(qa1.h, kb1.h, acc, 0, 0, 0);
    const int col = jt * 16 + colL;
#pragma unroll
    for (int r = 0; r < 4; ++r) {
      float e = 0.f;
      if (g + 64 * (12 + r) >= jt * 16) {         // reg not fully masked
        e = (col <= rowD[r]) ? __expf(acc[r] * 0.125f) : 0.f;
        sAcc[r] += e;
      }
      p[it][r] = e;
    }
  }
#pragma unroll
  for (int r = 0; r < 4; ++r) sAcc[r] = radd16(sAcc[r]);
  if (colL == 0) {
#pragma unroll
    for (int r = 0; r < 4; ++r) redS[kgrp * 4 + r][wv] = sAcc[r];
  }
  __syncthreads();
  float rs[4];
#pragma unroll
  for (int r = 0; r < 4; ++r) {
    const int m = kgrp * 4 + r;
    float S = 0.f;
#pragma unroll
    for (int w = 0; w < 16; ++w) S += redS[m][w];
    rs[r] = 1.25f / S;               // softmax denom + /(1-p) dropout scale
  }

  // ---- epilogue: P*rs + deterministic dropout, store all positions ----
#pragma unroll
  for (int it = 0; it < 4; ++it) {
    const int jt = it * 16 + wv;
#pragma unroll
    for (int r = 0; r < 4; ++r) {
      const int col = jt * 16 + colL;
      float v = 0.f;
      if (g + 64 * (12 + r) >= jt * 16) {         // skip threefry if masked
        const float e = (col <= rowD[r]) ? p[it][r] * rs[r] : 0.f;
        v = keep_at(obase[r] + (uint32_t)col) ? e : 0.f;
      }
      O[obase[r] + (uint32_t)col] = v;   // zeros clear the poison
    }
  }
}

extern "C" void kernel_launch(void* const* d_in, const int* in_sizes, int n_in,
                              void* d_out, int out_size, void* d_ws, size_t ws_size,
                              hipStream_t stream) {
  const float* q = (const float*)d_in[0];
  const float* k = (const float*)d_in[1];
  float* out = (float*)d_out;
  attn_kernel<<<dim3(BB * 64), 1024, 0, stream>>>(q, k, out);
}

// Round 21
// 25.165 us; speedup vs baseline: 1.0441x; 1.0441x over previous
//
#include <hip/hip_runtime.h>
#include <stdint.h>

// B=4, T=1024, D=64 causal attention probs + deterministic JAX dropout.
// R21 = composition of all three proven pieces:
//  cvt  (R18): Q,K -> f16 MFMA-fragment-major ws (coalesced hot-loop loads)
//  k1   (R17 structure): 1024 blocks x 256 thr (4 independent blocks/CU,
//        phase-staggered), block (g,cc) = 16 rows x 16 jt-tiles; E f16 +
//        per-(row,cc) sum partials (no atomics)
//  k2   (R16): 4096 blocks x 256 thr streaming dropout epilogue (16/CU)
// Independent blocks let one block's threefry overlap another's score phase
// (impossible in the single barrier-synced-block variants R13/R19).
#define TT 1024
#define BB 4

typedef __fp16 fp16x2 __attribute__((ext_vector_type(2)));
typedef __fp16 fp16x8 __attribute__((ext_vector_type(8)));
typedef float  floatx4 __attribute__((ext_vector_type(4)));
union U32H2 { uint32_t u; fp16x2 h; };
union U4H8  { uint4 u; fp16x8 h; };

__device__ __forceinline__ uint32_t rotl32(uint32_t x, int d) {
  return (x << d) | (x >> (32 - d));
}

// JAX partitionable threefry (key(42)): bits = o0^o1 of tf2x32((0,42),(0,i));
// keep = u<0.8f <=> bits < 6710887<<9.  [verified R1/R19]
__device__ __forceinline__ bool keep_at(uint32_t i) {
  uint32_t x0 = 0u, x1 = i;
  const uint32_t ks0 = 0u, ks1 = 42u;
  const uint32_t ks2 = 0x1BD11BDAu ^ ks0 ^ ks1;
  x0 += ks0; x1 += ks1;
#define R4(a,b,c,d)                              \
  x0 += x1; x1 = rotl32(x1,(a)); x1 ^= x0;       \
  x0 += x1; x1 = rotl32(x1,(b)); x1 ^= x0;       \
  x0 += x1; x1 = rotl32(x1,(c)); x1 ^= x0;       \
  x0 += x1; x1 = rotl32(x1,(d)); x1 ^= x0;
  R4(13,15,26,6)   x0 += ks1; x1 += ks2 + 1u;
  R4(17,29,16,24)  x0 += ks2; x1 += ks0 + 2u;
  R4(13,15,26,6)   x0 += ks0; x1 += ks1 + 3u;
  R4(17,29,16,24)  x0 += ks1; x1 += ks2 + 4u;
  R4(13,15,26,6)   x0 += ks2; x1 += ks0 + 5u;
#undef R4
  return (x0 ^ x1) < 3435974144u;   // 6710887 << 9
}

__device__ __forceinline__ uint32_t pack2(float x, float y) {
  U32H2 t; t.h = __builtin_amdgcn_cvt_pkrtz(x, y);
  return t.u;
}

template <int CTRL>
__device__ __forceinline__ float adddpp(float x) {
  const int s =
      __builtin_amdgcn_update_dpp(0, __float_as_int(x), CTRL, 0xF, 0xF, true);
  return x + __int_as_float(s);
}
// sum over the 16 lanes of a (l>>4) group  [verified R11-R20]
__device__ __forceinline__ float radd16(float a) {
  a = adddpp<0xB1>(a);  a = adddpp<0x4E>(a);
  a = adddpp<0x141>(a); a = adddpp<0x140>(a);
  return a;
}

// ---- cvt: Q,K -> f16 fragment-major  [verified R18] ----
__global__ __launch_bounds__(256)
void cvt_kernel(const float* __restrict__ Q, const float* __restrict__ K,
                uint32_t* __restrict__ W) {
  const int t = blockIdx.x * 256 + threadIdx.x;     // 0..65535
  uint4* W4 = reinterpret_cast<uint4*>(W);
  const bool isK = t >= 32768;
  const int t2 = t & 32767;
  const int ln = t2 & 63, c = (t2 >> 6) & 1, tile = (t2 >> 7) & 63, b = t2 >> 13;
  const int row = tile * (isK ? 16 : 1) + (isK ? (ln & 15) : 64 * (ln & 15));
  const float4* src = reinterpret_cast<const float4*>(isK ? K : Q) +
                      ((size_t)(b << 10) + row) * 16 + c * 8 + (ln >> 4) * 2;
  const float4 f0 = src[0], f1 = src[1];
  uint4 d;
  d.x = pack2(f0.x, f0.y); d.y = pack2(f0.z, f0.w);
  d.z = pack2(f1.x, f1.y); d.w = pack2(f1.z, f1.w);
  W4[t] = d;
}

// ---- k1: col-split MFMA scores (coalesced frag loads); E f16 + partials ----
__global__ __launch_bounds__(256)
void score_kernel(const uint32_t* __restrict__ W, _Float16* __restrict__ E,
                  float* __restrict__ SP) {
  __shared__ float redS[16][4];

  const int tid  = threadIdx.x;
  const int wv   = tid >> 6, ln = tid & 63;   // wv 0..3
  const int colL = ln & 15;
  const int kgrp = ln >> 4;
  const int cc   = blockIdx.x & 3;            // column chunk (16 jt tiles)
  const int g    = (blockIdx.x >> 2) & 63;
  const int b    = blockIdx.x >> 8;

  const uint4* W4 = reinterpret_cast<const uint4*>(W);
  const uint4* Qp = W4 + (size_t)b * 8192;            // [g][c][ln]
  const uint4* Kp = W4 + 32768 + (size_t)b * 8192;    // [jt][c][ln]

  U4H8 qa0, qa1;
  qa0.u = Qp[(g * 2 + 0) * 64 + ln];
  qa1.u = Qp[(g * 2 + 1) * 64 + ln];

  int rowD[4]; uint32_t obase[4];
#pragma unroll
  for (int r = 0; r < 4; ++r) {
    rowD[r]  = g + 64 * (kgrp * 4 + r);
    obase[r] = ((uint32_t)b << 20) | ((uint32_t)rowD[r] << 10);
  }

  float sAcc[4] = {0.f, 0.f, 0.f, 0.f};
#pragma unroll
  for (int it = 0; it < 4; ++it) {
    const int jt = cc * 16 + it * 4 + wv;
    U4H8 kb0, kb1;
    kb0.u = Kp[(jt * 2 + 0) * 64 + ln];
    kb1.u = Kp[(jt * 2 + 1) * 64 + ln];
    floatx4 acc = {0.f, 0.f, 0.f, 0.f};
    acc = __builtin_amdgcn_mfma_f32_16x16x32_f16(qa0.h, kb0.h, acc, 0, 0, 0);
    acc = __builtin_amdgcn_mfma_f32_16x16x32_f16(qa1.h, kb1.h, acc, 0, 0, 0);
    const int col = jt * 16 + colL;
#pragma unroll
    for (int r = 0; r < 4; ++r) {
      // fully-masked reg (max lane-row g+64*(12+r) < jt*16): skip entirely;
      // k2 never reads those positions (col > row there).
      if (g + 64 * (12 + r) >= jt * 16) {
        const float e = (col <= rowD[r]) ? __expf(acc[r] * 0.125f) : 0.f;
        sAcc[r] += e;
        E[obase[r] + (uint32_t)col] = (_Float16)e;
      }
    }
  }
#pragma unroll
  for (int r = 0; r < 4; ++r) sAcc[r] = radd16(sAcc[r]);
  if (colL == 0) {
#pragma unroll
    for (int r = 0; r < 4; ++r) redS[kgrp * 4 + r][wv] = sAcc[r];
  }
  __syncthreads();
  if (wv == 0 && colL == 0) {        // lanes 0,16,32,48 -> kgrp 0..3
#pragma unroll
    for (int r = 0; r < 4; ++r) {
      const int m = kgrp * 4 + r;
      const float S = redS[m][0] + redS[m][1] + redS[m][2] + redS[m][3];
      SP[(((b << 10) + g + 64 * m) << 2) + cc] = S;   // distinct slot per cc
    }
  }
}

// ---- k2: streaming dropout epilogue (16 blocks/CU)  [verified R16/R17] ----
__global__ __launch_bounds__(256)
void drop_kernel(const _Float16* __restrict__ E, const float* __restrict__ SP,
                 float* __restrict__ O) {
  const int gb  = blockIdx.x;          // b*1024 + row
  const int row = gb & 1023;
  const int tid = threadIdx.x;
  const uint32_t base = (uint32_t)gb << 10;
  const float4 sp = reinterpret_cast<const float4*>(SP)[gb];  // uniform
  const float rs = 1.25f / (sp.x + sp.y + sp.z + sp.w);
  const int col0 = tid * 4;

  float4 v = {0.f, 0.f, 0.f, 0.f};
  if ((tid & ~63) * 4 <= row) {        // wave-uniform skip
    const fp16x2* E2 = reinterpret_cast<const fp16x2*>(E + base + col0);
    const fp16x2 e01 = E2[0], e23 = E2[1];
    const uint32_t i0 = base + (uint32_t)col0;
    if (col0 + 0 <= row) v.x = keep_at(i0 + 0) ? (float)e01[0] * rs : 0.f;
    if (col0 + 1 <= row) v.y = keep_at(i0 + 1) ? (float)e01[1] * rs : 0.f;
    if (col0 + 2 <= row) v.z = keep_at(i0 + 2) ? (float)e23[0] * rs : 0.f;
    if (col0 + 3 <= row) v.w = keep_at(i0 + 3) ? (float)e23[1] * rs : 0.f;
  }
  *reinterpret_cast<float4*>(O + base + col0) = v;   // zeros clear the poison
}

extern "C" void kernel_launch(void* const* d_in, const int* in_sizes, int n_in,
                              void* d_out, int out_size, void* d_ws, size_t ws_size,
                              hipStream_t stream) {
  const float* q = (const float*)d_in[0];
  const float* k = (const float*)d_in[1];
  float* out = (float*)d_out;
  uint32_t* w = (uint32_t*)d_ws;                                   // 1 MB frags
  _Float16* E = (_Float16*)((char*)d_ws + (1 << 20));              // 8.4 MB
  float* SP = (float*)((char*)d_ws + (1 << 20) + (size_t)BB * TT * TT * 2);
  cvt_kernel<<<dim3(256), 256, 0, stream>>>(q, k, w);
  score_kernel<<<dim3(BB * 64 * 4), 256, 0, stream>>>(w, E, SP);
  drop_kernel<<<dim3(BB * TT), 256, 0, stream>>>(E, SP, out);
}

// Round 22
// 22.880 us; speedup vs baseline: 1.1484x; 1.0999x over previous
//
#include <hip/hip_runtime.h>
#include <stdint.h>

// B=4, T=1024, D=64 causal attention probs + deterministic JAX dropout.
// FINAL (R19 revert — best measured: 22.9 us).
// cvt: Q,K fp32 -> f16 MFMA-fragment-major ws (every hot-loop load is one
//      fully-coalesced dwordx4 per wave).
// attn: 256 blocks x 1024 thr; block = 16 interleaved rows {g+64m}; wave
//      owns 4 jt tiles; no-max softmax (q,k in [0,1) -> S in [0,8]);
//      e kept in p[4][4] VGPRs; DPP+LDS row sums; integer-compare threefry
//      dropout epilogue with fully-masked-tile skip.
#define TT 1024
#define BB 4

typedef __fp16 fp16x2 __attribute__((ext_vector_type(2)));
typedef __fp16 fp16x8 __attribute__((ext_vector_type(8)));
typedef float  floatx4 __attribute__((ext_vector_type(4)));
union U32H2 { uint32_t u; fp16x2 h; };
union U4H8  { uint4 u; fp16x8 h; };

__device__ __forceinline__ uint32_t rotl32(uint32_t x, int d) {
  return (x << d) | (x >> (32 - d));
}

// JAX partitionable threefry (key(42)): bits = o0^o1 of tf2x32((0,42),(0,i)).
// keep = u<0.8f  <=>  bits < 6710887<<9.  [verified R1/R19]
__device__ __forceinline__ bool keep_at(uint32_t i) {
  uint32_t x0 = 0u, x1 = i;
  const uint32_t ks0 = 0u, ks1 = 42u;
  const uint32_t ks2 = 0x1BD11BDAu ^ ks0 ^ ks1;
  x0 += ks0; x1 += ks1;
#define R4(a,b,c,d)                              \
  x0 += x1; x1 = rotl32(x1,(a)); x1 ^= x0;       \
  x0 += x1; x1 = rotl32(x1,(b)); x1 ^= x0;       \
  x0 += x1; x1 = rotl32(x1,(c)); x1 ^= x0;       \
  x0 += x1; x1 = rotl32(x1,(d)); x1 ^= x0;
  R4(13,15,26,6)   x0 += ks1; x1 += ks2 + 1u;
  R4(17,29,16,24)  x0 += ks2; x1 += ks0 + 2u;
  R4(13,15,26,6)   x0 += ks0; x1 += ks1 + 3u;
  R4(17,29,16,24)  x0 += ks1; x1 += ks2 + 4u;
  R4(13,15,26,6)   x0 += ks2; x1 += ks0 + 5u;
#undef R4
  return (x0 ^ x1) < 3435974144u;   // 6710887 << 9
}

__device__ __forceinline__ uint32_t pack2(float x, float y) {
  U32H2 t; t.h = __builtin_amdgcn_cvt_pkrtz(x, y);
  return t.u;
}

template <int CTRL>
__device__ __forceinline__ float adddpp(float x) {
  const int s =
      __builtin_amdgcn_update_dpp(0, __float_as_int(x), CTRL, 0xF, 0xF, true);
  return x + __int_as_float(s);
}
// sum over the 16 lanes of a (l>>4) group  [verified R11-R21]
__device__ __forceinline__ float radd16(float a) {
  a = adddpp<0xB1>(a);  a = adddpp<0x4E>(a);
  a = adddpp<0x141>(a); a = adddpp<0x140>(a);
  return a;
}

// ---- cvt: Q,K -> f16 fragment-major  [verified R18] ----
__global__ __launch_bounds__(256)
void cvt_kernel(const float* __restrict__ Q, const float* __restrict__ K,
                uint32_t* __restrict__ W) {
  const int t = blockIdx.x * 256 + threadIdx.x;     // 0..65535
  uint4* W4 = reinterpret_cast<uint4*>(W);
  const bool isK = t >= 32768;
  const int t2 = t & 32767;
  const int ln = t2 & 63, c = (t2 >> 6) & 1, tile = (t2 >> 7) & 63, b = t2 >> 13;
  const int row = tile * (isK ? 16 : 1) + (isK ? (ln & 15) : 64 * (ln & 15));
  const float4* src = reinterpret_cast<const float4*>(isK ? K : Q) +
                      ((size_t)(b << 10) + row) * 16 + c * 8 + (ln >> 4) * 2;
  const float4 f0 = src[0], f1 = src[1];
  uint4 d;
  d.x = pack2(f0.x, f0.y); d.y = pack2(f0.z, f0.w);
  d.z = pack2(f1.x, f1.y); d.w = pack2(f1.z, f1.w);
  W4[t] = d;
}

__global__ __launch_bounds__(1024)
void attn_kernel(const uint32_t* __restrict__ W, float* __restrict__ O) {
  __shared__ float redS[16][16];

  const int tid  = threadIdx.x;
  const int wv   = tid >> 6, ln = tid & 63;   // wv 0..15
  const int colL = ln & 15;
  const int kgrp = ln >> 4;
  const int g    = blockIdx.x & 63;
  const int b    = blockIdx.x >> 6;

  const uint4* W4 = reinterpret_cast<const uint4*>(W);
  const uint4* Qp = W4 + (size_t)b * 8192;            // [g][c][ln]
  const uint4* Kp = W4 + 32768 + (size_t)b * 8192;    // [jt][c][ln]

  U4H8 qa0, qa1;
  qa0.u = Qp[(g * 2 + 0) * 64 + ln];
  qa1.u = Qp[(g * 2 + 1) * 64 + ln];

  int rowD[4]; uint32_t obase[4];
#pragma unroll
  for (int r = 0; r < 4; ++r) {
    rowD[r]  = g + 64 * (kgrp * 4 + r);
    obase[r] = ((uint32_t)b << 20) | ((uint32_t)rowD[r] << 10);
  }

  // ---- pass A: 4 jt tiles per wave, coalesced B-frag loads ----
  float p[4][4];
  float sAcc[4] = {0.f, 0.f, 0.f, 0.f};
#pragma unroll
  for (int it = 0; it < 4; ++it) {
    const int jt = it * 16 + wv;
    U4H8 kb0, kb1;
    kb0.u = Kp[(jt * 2 + 0) * 64 + ln];
    kb1.u = Kp[(jt * 2 + 1) * 64 + ln];
    floatx4 acc = {0.f, 0.f, 0.f, 0.f};
    acc = __builtin_amdgcn_mfma_f32_16x16x32_f16(qa0.h, kb0.h, acc, 0, 0, 0);
    acc = __builtin_amdgcn_mfma_f32_16x16x32_f16(qa1.h, kb1.h, acc, 0, 0, 0);
    const int col = jt * 16 + colL;
#pragma unroll
    for (int r = 0; r < 4; ++r) {
      const float e = (col <= rowD[r]) ? __expf(acc[r] * 0.125f) : 0.f;
      p[it][r] = e;
      sAcc[r] += e;
    }
  }
#pragma unroll
  for (int r = 0; r < 4; ++r) sAcc[r] = radd16(sAcc[r]);
  if (colL == 0) {
#pragma unroll
    for (int r = 0; r < 4; ++r) redS[kgrp * 4 + r][wv] = sAcc[r];
  }
  __syncthreads();
  float rs[4];
#pragma unroll
  for (int r = 0; r < 4; ++r) {
    const int m = kgrp * 4 + r;
    float S = 0.f;
#pragma unroll
    for (int w = 0; w < 16; ++w) S += redS[m][w];
    rs[r] = 1.25f / S;               // softmax denom + /(1-p) dropout scale
  }

  // ---- epilogue: P*rs + deterministic dropout, store all positions ----
#pragma unroll
  for (int it = 0; it < 4; ++it) {
    const int jt = it * 16 + wv;
#pragma unroll
    for (int r = 0; r < 4; ++r) {
      const int col = jt * 16 + colL;
      float v = 0.f;
      // reg fully masked iff max lane-row (g+64*(12+r)) < jt*16 -> skip threefry
      if (g + 64 * (12 + r) >= jt * 16) {
        const float e = (col <= rowD[r]) ? p[it][r] * rs[r] : 0.f;
        v = keep_at(obase[r] + (uint32_t)col) ? e : 0.f;
      }
      O[obase[r] + (uint32_t)col] = v;   // zeros clear the poison
    }
  }
}

extern "C" void kernel_launch(void* const* d_in, const int* in_sizes, int n_in,
                              void* d_out, int out_size, void* d_ws, size_t ws_size,
                              hipStream_t stream) {
  const float* q = (const float*)d_in[0];
  const float* k = (const float*)d_in[1];
  float* out = (float*)d_out;
  uint32_t* w = (uint32_t*)d_ws;     // 1 MB fragment-major staging
  cvt_kernel<<<dim3(256), 256, 0, stream>>>(q, k, w);
  attn_kernel<<<dim3(BB * 64), 1024, 0, stream>>>(w, out);
}